// Round 7
// baseline (106.866 us; speedup 1.0000x reference)
//
#include <hip/hip_runtime.h>
#include <stdint.h>

// ---------------------------------------------------------------------------
// NT-Xent loss, B=8 S=512 D=128  ->  N=4096, 2N=8192 rows, K=128.
// loss = mean_i( -pos_i + log(sum_{j!=i} exp(sim_ij)) ),  sim = z_n z_n^T / T
//
// v8: v7's 512-thread / one-LDS-stage / one-barrier structure (8 waves/SIMD
// occupancy, the v7 win), but wave quadrants go 16x128 -> 32x64
// (rowgroup=w>>1, colgroup=w&1).  B-fragment LDS reads halve: 8 waves x 16
// ds_read_b128 = 128/block (was 256), cutting the dominant throughput term
// (LDS pipe ~10.4 us -> ~5.2 us model).  A-fragments double to 2 strips
// (32 VGPR) and A global traffic doubles (~+66 MB over L2 -- cheap).  Inner
// loop is k-chunked (2 B-frags live) to hold total VGPR ~= 64 so 8
// waves/SIMD are kept.  Row partials span 2 waves, col partials 4 -> 3 KB
// LDS epilogue combine; scratch layout unchanged.
//
//  k1: normalize rows (fp32), pos_half in fp32, store z_n * SCALE as bf16
//      where SCALE^2 = log2(e)/T, so MFMA acc = sim*log2e and
//      exp(sim) == exp2(acc) == one v_exp_f32.
//  k2: symmetric Gram + exp row/col partial sums -> scratch[blk][256].
//  k3: ntx_redu: rowsum_i = sum of 64 block partials (triangular indexing).
//  k4: ntx_final: loss = (sum lpart - 2*sum pos_half) / 8192.
// No max-subtraction needed: logits in [-14.3,14.3], sums < 1.3e10 (fp32-safe).
// ---------------------------------------------------------------------------

#define TOTAL   8192
#define NHALF   4096
#define DK      128
#define TEMP_INV 14.285714285714286f
#define SCALE    4.539816f      // sqrt(log2(e)/0.07); SCALE^2 = 20.609929

#define TILE    128                       // square tile edge
#define TILES   (TOTAL / TILE)            // 64
#define NBLK    (TILES * (TILES + 1) / 2) // 2080 super-diagonal tiles
#define WAVES   8

typedef short  bf16x8  __attribute__((ext_vector_type(8)));
typedef float  floatx4 __attribute__((ext_vector_type(4)));

#if __has_builtin(__builtin_amdgcn_exp2f)
#define EXP2(x) __builtin_amdgcn_exp2f(x)
#else
#define EXP2(x) exp2f(x)
#endif

__device__ __forceinline__ uint32_t f2bf(float f) {
  uint32_t u = __float_as_uint(f);
  return (u + 0x7fffu + ((u >> 16) & 1u)) >> 16;   // RNE; inputs finite
}
__device__ __forceinline__ uint32_t pack2bf(float lo, float hi) {
  return f2bf(lo) | (f2bf(hi) << 16);
}

// --------------------------- kernel 1: normalize ---------------------------
// grid 1024 x 256. Each wave handles one i (both z_i and z_j rows).
__global__ __launch_bounds__(256) void ntx_norm(
    const float* __restrict__ zi, const float* __restrict__ zj,
    uint32_t* __restrict__ zn,   // packed 2xbf16, [TOTAL][64]
    float* __restrict__ pos)     // [NHALF]
{
  const int t = threadIdx.x;
  const int wave = t >> 6, lane = t & 63;
  const int i = blockIdx.x * 4 + wave;

  const float2 vi = *(const float2*)(zi + (size_t)i * DK + lane * 2);
  const float2 vj = *(const float2*)(zj + (size_t)i * DK + lane * 2);
  float ssi = vi.x * vi.x + vi.y * vi.y;
  float ssj = vj.x * vj.x + vj.y * vj.y;
  float dij = vi.x * vj.x + vi.y * vj.y;
#pragma unroll
  for (int m = 1; m <= 32; m <<= 1) {
    ssi += __shfl_xor(ssi, m, 64);
    ssj += __shfl_xor(ssj, m, 64);
    dij += __shfl_xor(dij, m, 64);
  }
  const float invi = 1.0f / fmaxf(sqrtf(ssi), 1e-12f);
  const float invj = 1.0f / fmaxf(sqrtf(ssj), 1e-12f);

  zn[(size_t)i * 64 + lane] =
      pack2bf(vi.x * invi * SCALE, vi.y * invi * SCALE);
  zn[(size_t)(i + NHALF) * 64 + lane] =
      pack2bf(vj.x * invj * SCALE, vj.y * invj * SCALE);
  if (lane == 0) pos[i] = dij * invi * invj * TEMP_INV;
}

// ---------------- kernel 2: symmetric Gram + exp partial sums --------------
// grid NBLK x 512. Linear block id -> upper-triangular tile (I, J), J >= I.
// Wave w: rowgroup rg=w>>1 (32 rows), colgroup cg=w&1 (64 cols).
// Fragment layout (verified): frag[k=q*8+kk*32+j][m-or-n=c]
//   A -> z[rowbase+s*16+c][kk*32+q*8 ..+8] ; B -> lds row, 16B chunk (kk*4+q)
__global__ __launch_bounds__(512, 8) void ntx_gemm(
    const uint16_t* __restrict__ z,   // [TOTAL][DK] bf16 (scaled)
    float* __restrict__ scratch)      // [NBLK][256]: 128 row + 128 col parts
{
  __shared__ uint4 lb4[TILE * 17];    // 128 rows x (256B data + 16B pad)
  __shared__ float rowacc[WAVES][32];
  __shared__ float colacc[WAVES][64];

  // map linear block id -> (I, J) with J >= I  (row-major upper triangle)
  int I = 0, rem = (int)blockIdx.x, span = TILES;
  while (rem >= span) { rem -= span; --span; ++I; }
  const int J = I + rem;
  const bool isdiag = (I == J);

  const int t = threadIdx.x;
  const int w = t >> 6, lane = t & 63;
  const int q = lane >> 4, c = lane & 15;
  const int rg = w >> 1, cg = w & 1;
  const int i0 = I * TILE;
  const int j0 = J * TILE;
  const int rowbase = i0 + rg * 32;
  const int colbase = j0 + cg * 64;

  // A fragments: 2 strips x 4 k-steps (issue before staging so the
  // scattered-load latency hides under the stage + barrier).
  bf16x8 afrag[2][4];
#pragma unroll
  for (int s = 0; s < 2; ++s) {
    const uint16_t* ap = z + (size_t)(rowbase + s * 16 + c) * DK + q * 8;
#pragma unroll
    for (int kk = 0; kk < 4; ++kk)
      afrag[s][kk] = *(const bf16x8*)(ap + kk * 32);
  }

  // stage the full B panel (rows j0..j0+127 of z), coalesced 16B/thread.
  {
    const int r0 = t >> 4, ch = t & 15;
#pragma unroll
    for (int p = 0; p < 4; ++p) {
      const int r = r0 + p * 32;
      lb4[r * 17 + ch] = *(const uint4*)(z + (size_t)(j0 + r) * DK + ch * 8);
    }
  }
  __syncthreads();

  float runsum[2][4];
#pragma unroll
  for (int s = 0; s < 2; ++s)
#pragma unroll
    for (int r = 0; r < 4; ++r) runsum[s][r] = 0.0f;

#pragma unroll
  for (int jt = 0; jt < 4; ++jt) {
    const int jc = colbase + jt * 16;           // col = jc + c
    const int ldsrow = (cg * 64 + jt * 16 + c) * 17;

    floatx4 acc0 = {0.0f, 0.0f, 0.0f, 0.0f};
    floatx4 acc1 = {0.0f, 0.0f, 0.0f, 0.0f};
    // k-chunked: only 2 B-fragments live at a time (VGPR <= 64 for 8 w/SIMD)
#pragma unroll
    for (int kh = 0; kh < 2; ++kh) {
      const bf16x8 b0 = *(const bf16x8*)&lb4[ldsrow + (kh * 2 + 0) * 4 + q];
      const bf16x8 b1 = *(const bf16x8*)&lb4[ldsrow + (kh * 2 + 1) * 4 + q];
      acc0 = __builtin_amdgcn_mfma_f32_16x16x32_bf16(afrag[0][kh * 2 + 0], b0,
                                                     acc0, 0, 0, 0);
      acc0 = __builtin_amdgcn_mfma_f32_16x16x32_bf16(afrag[0][kh * 2 + 1], b1,
                                                     acc0, 0, 0, 0);
      acc1 = __builtin_amdgcn_mfma_f32_16x16x32_bf16(afrag[1][kh * 2 + 0], b0,
                                                     acc1, 0, 0, 0);
      acc1 = __builtin_amdgcn_mfma_f32_16x16x32_bf16(afrag[1][kh * 2 + 1], b1,
                                                     acc1, 0, 0, 0);
    }

    float colv = 0.0f;
    // strip 0 (rows rowbase..+16)
    if (isdiag && jc == rowbase) {
#pragma unroll
      for (int r = 0; r < 4; ++r) {
        float e = EXP2(acc0[r]);
        runsum[0][r] += (q * 4 + r == c) ? 0.0f : e;
      }
    } else {
#pragma unroll
      for (int r = 0; r < 4; ++r) {
        float e = EXP2(acc0[r]);
        runsum[0][r] += e;
        colv += e;
      }
    }
    // strip 1 (rows rowbase+16..+32)
    if (isdiag && jc == rowbase + 16) {
#pragma unroll
      for (int r = 0; r < 4; ++r) {
        float e = EXP2(acc1[r]);
        runsum[1][r] += (q * 4 + r == c) ? 0.0f : e;
      }
    } else {
#pragma unroll
      for (int r = 0; r < 4; ++r) {
        float e = EXP2(acc1[r]);
        runsum[1][r] += e;
        colv += e;
      }
    }

    if (!isdiag) {
      // col sums over this wave's 32 rows: combine the 4 q-groups
      colv += __shfl_xor(colv, 16, 64);
      colv += __shfl_xor(colv, 32, 64);
      if (lane < 16) colacc[w][jt * 16 + lane] = colv;
    }
  }

  // row partials: reduce across the 16 c-lanes (same q) -> LDS
#pragma unroll
  for (int s = 0; s < 2; ++s)
#pragma unroll
    for (int r = 0; r < 4; ++r) {
      float v = runsum[s][r];
      v += __shfl_xor(v, 1, 64);
      v += __shfl_xor(v, 2, 64);
      v += __shfl_xor(v, 4, 64);
      v += __shfl_xor(v, 8, 64);
      if (c == 0) rowacc[w][s * 16 + q * 4 + r] = v;
    }

  __syncthreads();
  // combine waves; store per block.  rows: rg = t>>5, both colgroups.
  // cols: cg = t>>6, all 4 rowgroups.
  float* sblk = scratch + (size_t)blockIdx.x * 256;
  if (t < TILE) {
    const int rrg = t >> 5, ro = t & 31;
    sblk[t] = rowacc[2 * rrg][ro] + rowacc[2 * rrg + 1][ro];
    if (!isdiag) {
      const int ccg = t >> 6, co = t & 63;
      sblk[128 + t] = colacc[ccg][co] + colacc[ccg + 2][co] +
                      colacc[ccg + 4][co] + colacc[ccg + 6][co];
    }
  }
}

// ------------------- kernel 3: gather partials, log-reduce -----------------
// grid 64 x 256. Block I handles rows [128I, 128I+128).
// rowsum_i = sum_{J=I..63} scratch[id(I,J)][o] + sum_{I'<I} scratch[id(I',I)][128+o]
// id(I,J) = I*64 - I(I-1)/2 + (J-I);  id(I'+1,I) - id(I',I) = 63 - I'.
// Threads 0..127 gather the row-partial loop, 128..255 the col-partial loop.
__global__ __launch_bounds__(256) void ntx_redu(
    const float* __restrict__ scratch, float* __restrict__ lpart)
{
  __shared__ float sbuf[128];
  __shared__ float red[2];

  const int I = (int)blockIdx.x;
  const int o = (int)threadIdx.x & 127;
  const int half = (int)threadIdx.x >> 7;

  float S = 0.0f;
  if (half == 0) {
    int id = I * TILES - (I * (I - 1)) / 2;      // id(I, I)
#pragma unroll 8
    for (int Jt = I; Jt < TILES; ++Jt, ++id)
      S += scratch[(size_t)id * 256 + o];
  } else {
    int idc = I;                                  // id(0, I)
#pragma unroll 8
    for (int Ip = 0; Ip < I; ++Ip) {
      S += scratch[(size_t)idc * 256 + 128 + o];
      idc += TILES - 1 - Ip;
    }
  }
  if (half) sbuf[o] = S;
  __syncthreads();
  if (!half) {
    float v = __logf(S + sbuf[o]);
#pragma unroll
    for (int m = 1; m <= 32; m <<= 1) v += __shfl_xor(v, m, 64);
    if ((o & 63) == 0) red[o >> 6] = v;
  }
  __syncthreads();
  if (threadIdx.x == 0) lpart[I] = red[0] + red[1];
}

// --------------------------- kernel 4: finalize ----------------------------
__global__ __launch_bounds__(256) void ntx_final(
    const float* __restrict__ lpart, const float* __restrict__ pos,
    float* __restrict__ out)
{
  const int t = threadIdx.x;
  float acc = (t < TILES) ? lpart[t] : 0.0f;
  for (int r = t; r < NHALF; r += 256) acc -= 2.0f * pos[r];
#pragma unroll
  for (int m = 1; m <= 32; m <<= 1) acc += __shfl_xor(acc, m, 64);
  __shared__ float red[4];
  if ((t & 63) == 0) red[t >> 6] = acc;
  __syncthreads();
  if (t == 0) out[0] = (red[0] + red[1] + red[2] + red[3]) / (float)TOTAL;
}

// ---------------------------------------------------------------------------
extern "C" void kernel_launch(void* const* d_in, const int* in_sizes, int n_in,
                              void* d_out, int out_size, void* d_ws,
                              size_t ws_size, hipStream_t stream) {
  const float* zi = (const float*)d_in[0];
  const float* zj = (const float*)d_in[1];
  float* out = (float*)d_out;

  char* ws = (char*)d_ws;
  uint16_t* zn      = (uint16_t*)ws;                          // 2 MiB bf16
  float*    scratch = (float*)(ws + (size_t)TOTAL * DK * 2);  // 2.13 MB
  float*    lpart   = (float*)(ws + (size_t)TOTAL * DK * 2
                               + (size_t)NBLK * 256 * 4);     // 256 B
  float*    pos     = (float*)(ws + (size_t)TOTAL * DK * 2
                               + (size_t)NBLK * 256 * 4 + 256);  // 16 KB

  ntx_norm<<<dim3(NHALF / 4), dim3(256), 0, stream>>>(zi, zj, (uint32_t*)zn,
                                                      pos);
  ntx_gemm<<<dim3(NBLK), dim3(512), 0, stream>>>(zn, scratch);
  ntx_redu<<<dim3(TILES), dim3(256), 0, stream>>>(scratch, lpart);
  ntx_final<<<dim3(1), dim3(256), 0, stream>>>(lpart, pos, out);
}

// Round 8
// 92.310 us; speedup vs baseline: 1.1577x; 1.1577x over previous
//
#include <hip/hip_runtime.h>
#include <stdint.h>

// ---------------------------------------------------------------------------
// NT-Xent loss, B=8 S=512 D=128  ->  N=4096, 2N=8192 rows, K=128.
// loss = mean_i( -pos_i + log(sum_{j!=i} exp(sim_ij)) ),  sim = z_n z_n^T / T
//
// v9: gemm reverted to EXACT v7 (best measured: 512 thr / 8 waves/SIMD, one
// LDS stage of the 128-col B panel, one barrier, wave = 16 rows x 128 cols).
// v8's "halve LDS reads" variants regressed twice -> LDS pipe is not the
// binding constraint; v7's low-VGPR high-TLP point stands.  This round
// removes fixed overhead instead: ntx_redu and ntx_final are fused via the
// last-block pattern (device-scope atomic ticket; deterministic final sum),
// cutting one kernel launch + dispatch drain.
//
//  k1: normalize rows (fp32), pos_half in fp32, store z_n * SCALE as bf16
//      where SCALE^2 = log2(e)/T, so MFMA acc = sim*log2e and
//      exp(sim) == exp2(acc) == one v_exp_f32.  Also zeroes the ticket.
//  k2: symmetric Gram + exp row/col partial sums -> scratch[blk][256]
//      (2080 upper-triangle 128x128 tiles; no atomics).
//  k3: ntx_redufin: block I gathers the 64 partials per row (triangular
//      indexing), lpart[I] = sum log(rowsum); last block (ticket==63)
//      deterministically reduces lpart[0..63] - 2*sum(pos) -> out.
// No max-subtraction needed: logits in [-14.3,14.3], sums < 1.3e10 (fp32-safe).
// ---------------------------------------------------------------------------

#define TOTAL   8192
#define NHALF   4096
#define DK      128
#define TEMP_INV 14.285714285714286f
#define SCALE    4.539816f      // sqrt(log2(e)/0.07); SCALE^2 = 20.609929

#define TILE    128                       // square tile edge
#define TILES   (TOTAL / TILE)            // 64
#define NBLK    (TILES * (TILES + 1) / 2) // 2080 super-diagonal tiles
#define WAVES   8

typedef short  bf16x8  __attribute__((ext_vector_type(8)));
typedef float  floatx4 __attribute__((ext_vector_type(4)));

#if __has_builtin(__builtin_amdgcn_exp2f)
#define EXP2(x) __builtin_amdgcn_exp2f(x)
#else
#define EXP2(x) exp2f(x)
#endif

__device__ __forceinline__ uint32_t f2bf(float f) {
  uint32_t u = __float_as_uint(f);
  return (u + 0x7fffu + ((u >> 16) & 1u)) >> 16;   // RNE; inputs finite
}
__device__ __forceinline__ uint32_t pack2bf(float lo, float hi) {
  return f2bf(lo) | (f2bf(hi) << 16);
}

// --------------------------- kernel 1: normalize ---------------------------
// grid 1024 x 256. Each wave handles one i (both z_i and z_j rows).
__global__ __launch_bounds__(256) void ntx_norm(
    const float* __restrict__ zi, const float* __restrict__ zj,
    uint32_t* __restrict__ zn,   // packed 2xbf16, [TOTAL][64]
    float* __restrict__ pos,     // [NHALF]
    unsigned* __restrict__ ticket)
{
  const int t = threadIdx.x;
  if (blockIdx.x == 0 && t == 0) ticket[0] = 0u;   // re-arm last-block gate

  const int wave = t >> 6, lane = t & 63;
  const int i = blockIdx.x * 4 + wave;

  const float2 vi = *(const float2*)(zi + (size_t)i * DK + lane * 2);
  const float2 vj = *(const float2*)(zj + (size_t)i * DK + lane * 2);
  float ssi = vi.x * vi.x + vi.y * vi.y;
  float ssj = vj.x * vj.x + vj.y * vj.y;
  float dij = vi.x * vj.x + vi.y * vj.y;
#pragma unroll
  for (int m = 1; m <= 32; m <<= 1) {
    ssi += __shfl_xor(ssi, m, 64);
    ssj += __shfl_xor(ssj, m, 64);
    dij += __shfl_xor(dij, m, 64);
  }
  const float invi = 1.0f / fmaxf(sqrtf(ssi), 1e-12f);
  const float invj = 1.0f / fmaxf(sqrtf(ssj), 1e-12f);

  zn[(size_t)i * 64 + lane] =
      pack2bf(vi.x * invi * SCALE, vi.y * invi * SCALE);
  zn[(size_t)(i + NHALF) * 64 + lane] =
      pack2bf(vj.x * invj * SCALE, vj.y * invj * SCALE);
  if (lane == 0) pos[i] = dij * invi * invj * TEMP_INV;
}

// ---------------- kernel 2: symmetric Gram + exp partial sums --------------
// grid NBLK x 512. Linear block id -> upper-triangular tile (I, J), J >= I.
// Wave w owns rows [i0+16w, i0+16w+16) x all 128 cols.   (EXACT v7 body.)
// Fragment layout (verified): frag[k=q*8+kk*32+j][m-or-n=c]
//   A -> z[rowbase+c][kk*32+q*8 ..+8] ; B -> lds row (jt*16+c), 16B (kk*4+q)
__global__ __launch_bounds__(512, 8) void ntx_gemm(
    const uint16_t* __restrict__ z,   // [TOTAL][DK] bf16 (scaled)
    float* __restrict__ scratch)      // [NBLK][256]: 128 row + 128 col parts
{
  __shared__ uint4 lb4[TILE * 17];    // 128 rows x (256B data + 16B pad)
  __shared__ float colacc[WAVES][TILE];

  // map linear block id -> (I, J) with J >= I  (row-major upper triangle)
  int I = 0, rem = (int)blockIdx.x, span = TILES;
  while (rem >= span) { rem -= span; --span; ++I; }
  const int J = I + rem;
  const bool isdiag = (I == J);

  const int t = threadIdx.x;
  const int w = t >> 6, lane = t & 63;
  const int q = lane >> 4, c = lane & 15;
  const int i0 = I * TILE;
  const int j0 = J * TILE;
  const int rowbase = i0 + w * 16;

  // A fragment: this wave's 16 rows, 4 k-steps (issue before staging so the
  // scattered-load latency hides under the stage + barrier).
  bf16x8 afrag[4];
  {
    const uint16_t* ap = z + (size_t)(rowbase + c) * DK + q * 8;
#pragma unroll
    for (int kk = 0; kk < 4; ++kk)
      afrag[kk] = *(const bf16x8*)(ap + kk * 32);
  }

  // stage the full B panel (rows j0..j0+127 of z), coalesced 16B/thread.
  {
    const int r0 = t >> 4, ch = t & 15;
#pragma unroll
    for (int p = 0; p < 4; ++p) {
      const int r = r0 + p * 32;
      lb4[r * 17 + ch] = *(const uint4*)(z + (size_t)(j0 + r) * DK + ch * 8);
    }
  }
  __syncthreads();

  float runsum[4] = {0.0f, 0.0f, 0.0f, 0.0f};

#pragma unroll
  for (int jt = 0; jt < TILE / 16; ++jt) {
    const int jc = j0 + jt * 16;       // col = jc + c
    bf16x8 bfrag[4];
#pragma unroll
    for (int kk = 0; kk < 4; ++kk)
      bfrag[kk] = *(const bf16x8*)&lb4[(jt * 16 + c) * 17 + kk * 4 + q];

    floatx4 acc = {0.0f, 0.0f, 0.0f, 0.0f};
#pragma unroll
    for (int kk = 0; kk < 4; ++kk)
      acc = __builtin_amdgcn_mfma_f32_16x16x32_bf16(afrag[kk], bfrag[kk],
                                                    acc, 0, 0, 0);
    // row = rowbase + q*4 + r
    if (isdiag && jc == rowbase) {       // diagonal 16x16 (wave-uniform)
#pragma unroll
      for (int r = 0; r < 4; ++r) {
        float e = EXP2(acc[r]);
        runsum[r] += (q * 4 + r == c) ? 0.0f : e;
      }
    } else {
      float colv = 0.0f;
#pragma unroll
      for (int r = 0; r < 4; ++r) {
        float e = EXP2(acc[r]);
        runsum[r] += e;
        colv += e;
      }
      if (!isdiag) {
        // col sums over this wave's 16 rows: combine the 4 q-groups
        colv += __shfl_xor(colv, 16, 64);
        colv += __shfl_xor(colv, 32, 64);
        if (lane < 16) colacc[w][jt * 16 + lane] = colv;
      }
    }
  }

  // row partials: reduce across the 16 c-lanes (same q), store per block
  float* sblk = scratch + (size_t)blockIdx.x * 256;
#pragma unroll
  for (int r = 0; r < 4; ++r) {
    float v = runsum[r];
    v += __shfl_xor(v, 1, 64);
    v += __shfl_xor(v, 2, 64);
    v += __shfl_xor(v, 4, 64);
    v += __shfl_xor(v, 8, 64);
    if (c == 0) sblk[w * 16 + q * 4 + r] = v;
  }

  // column partials: combine the 8 waves (off-diagonal blocks only)
  __syncthreads();
  if (!isdiag && t < TILE) {
    float s = 0.0f;
#pragma unroll
    for (int ww = 0; ww < WAVES; ++ww) s += colacc[ww][t];
    sblk[128 + t] = s;
  }
}

// ------------- kernel 3: gather partials, log-reduce, finalize -------------
// grid 64 x 256. Block I handles rows [128I, 128I+128).
// rowsum_i = sum_{J=I..63} scratch[id(I,J)][o] + sum_{I'<I} scratch[id(I',I)][128+o]
// id(I,J) = I*64 - I(I-1)/2 + (J-I);  id(I'+1,I) - id(I',I) = 63 - I'.
// Threads 0..127 gather the row-partial loop, 128..255 the col-partial loop.
// Last block to finish (device-scope ticket) reduces lpart + pos -> out.
__global__ __launch_bounds__(256) void ntx_redufin(
    const float* __restrict__ scratch, const float* __restrict__ pos,
    float* __restrict__ lpart, unsigned* __restrict__ ticket,
    float* __restrict__ out)
{
  __shared__ float sbuf[128];
  __shared__ float red[4];
  __shared__ int amLast;

  const int I = (int)blockIdx.x;
  const int t = (int)threadIdx.x;
  const int o = t & 127;
  const int half = t >> 7;

  float S = 0.0f;
  if (half == 0) {
    int id = I * TILES - (I * (I - 1)) / 2;      // id(I, I)
#pragma unroll 8
    for (int Jt = I; Jt < TILES; ++Jt, ++id)
      S += scratch[(size_t)id * 256 + o];
  } else {
    int idc = I;                                  // id(0, I)
#pragma unroll 8
    for (int Ip = 0; Ip < I; ++Ip) {
      S += scratch[(size_t)idc * 256 + 128 + o];
      idc += TILES - 1 - Ip;
    }
  }
  if (half) sbuf[o] = S;
  __syncthreads();
  if (!half) {
    float v = __logf(S + sbuf[o]);
#pragma unroll
    for (int m = 1; m <= 32; m <<= 1) v += __shfl_xor(v, m, 64);
    if ((o & 63) == 0) red[o >> 6] = v;
  }
  __syncthreads();
  if (t == 0) {
    atomicExch(&lpart[I], red[0] + red[1]);   // device-scope store
    __threadfence();                          // release before ticket
    const unsigned done = atomicAdd(ticket, 1u);
    amLast = (done == (unsigned)(TILES - 1));
  }
  __syncthreads();
  if (!amLast) return;

  // ---- last block: deterministic final reduction ----
  __threadfence();                            // acquire side
  float acc = 0.0f;
  if (t < TILES) acc = atomicAdd(&lpart[t], 0.0f);   // coherent read
  for (int r = t; r < NHALF; r += 256) acc -= 2.0f * pos[r];
#pragma unroll
  for (int m = 1; m <= 32; m <<= 1) acc += __shfl_xor(acc, m, 64);
  __syncthreads();                            // red[] reuse
  if ((t & 63) == 0) red[t >> 6] = acc;
  __syncthreads();
  if (t == 0) out[0] = (red[0] + red[1] + red[2] + red[3]) / (float)TOTAL;
}

// ---------------------------------------------------------------------------
extern "C" void kernel_launch(void* const* d_in, const int* in_sizes, int n_in,
                              void* d_out, int out_size, void* d_ws,
                              size_t ws_size, hipStream_t stream) {
  const float* zi = (const float*)d_in[0];
  const float* zj = (const float*)d_in[1];
  float* out = (float*)d_out;

  char* ws = (char*)d_ws;
  uint16_t* zn      = (uint16_t*)ws;                          // 2 MiB bf16
  size_t off = (size_t)TOTAL * DK * 2;
  float*    scratch = (float*)(ws + off);                     // 2.13 MB
  off += (size_t)NBLK * 256 * 4;
  float*    lpart   = (float*)(ws + off);                     // 256 B
  off += 256 * 4;
  float*    pos     = (float*)(ws + off);                     // 16 KB
  off += (size_t)NHALF * 4;
  unsigned* ticket  = (unsigned*)(ws + off);                  // 4 B

  ntx_norm<<<dim3(NHALF / 4), dim3(256), 0, stream>>>(zi, zj, (uint32_t*)zn,
                                                      pos, ticket);
  ntx_gemm<<<dim3(NBLK), dim3(512), 0, stream>>>(zn, scratch);
  ntx_redufin<<<dim3(TILES), dim3(256), 0, stream>>>(scratch, pos, lpart,
                                                     ticket, out);
}

// Round 9
// 90.337 us; speedup vs baseline: 1.1830x; 1.0218x over previous
//
#include <hip/hip_runtime.h>
#include <stdint.h>

// ---------------------------------------------------------------------------
// NT-Xent loss, B=8 S=512 D=128  ->  N=4096, 2N=8192 rows, K=128.
// loss = mean_i( -pos_i + log(sum_{j!=i} exp(sim_ij)) ),  sim = z_n z_n^T / T
//
// v10: consolidation.  gemm = EXACT v7/v9 body (best measured: 512 thr /
// 8 waves/SIMD via launch_bounds(512,8), one LDS stage of the 128-col B
// panel, one barrier, wave = 16 rows x 128 cols) -- occupancy was the only
// lever that ever moved it; all per-wave restructures regressed.  This round
// harvests certain micro-wins only:
//   * closed-form (I,J) triangle decode (sqrtf + fixup) replaces the up-to-
//     63-iteration serial decode loop at every block start.
//   * ntx_redufin widened to 512 thr / 4 gather groups: halves the serial
//     per-thread L2 gather chain of the tail kernel.
//
//  k1: normalize rows (fp32), pos_half in fp32, store z_n * SCALE as bf16
//      where SCALE^2 = log2(e)/T, so MFMA acc = sim*log2e and
//      exp(sim) == exp2(acc) == one v_exp_f32.  Also re-arms the ticket.
//  k2: symmetric Gram + exp row/col partial sums -> scratch[blk][256]
//      (2080 upper-triangle 128x128 tiles; no atomics).
//  k3: ntx_redufin: block I gathers the 64 partials per row (triangular
//      indexing, 4-way split), lpart[I] = sum log(rowsum); last block
//      (ticket) deterministically reduces lpart[0..63] - 2*sum(pos) -> out.
// No max-subtraction needed: logits in [-14.3,14.3], sums < 1.3e10 (fp32-safe).
// ---------------------------------------------------------------------------

#define TOTAL   8192
#define NHALF   4096
#define DK      128
#define TEMP_INV 14.285714285714286f
#define SCALE    4.539816f      // sqrt(log2(e)/0.07); SCALE^2 = 20.609929

#define TILE    128                       // square tile edge
#define TILES   (TOTAL / TILE)            // 64
#define NBLK    (TILES * (TILES + 1) / 2) // 2080 super-diagonal tiles
#define WAVES   8

// TRI(I) = number of tiles before row I = I*(2*TILES+1-I)/2, TILES=64
#define TRI(I) (((I) * (129 - (I))) >> 1)

typedef short  bf16x8  __attribute__((ext_vector_type(8)));
typedef float  floatx4 __attribute__((ext_vector_type(4)));

#if __has_builtin(__builtin_amdgcn_exp2f)
#define EXP2(x) __builtin_amdgcn_exp2f(x)
#else
#define EXP2(x) exp2f(x)
#endif

__device__ __forceinline__ uint32_t f2bf(float f) {
  uint32_t u = __float_as_uint(f);
  return (u + 0x7fffu + ((u >> 16) & 1u)) >> 16;   // RNE; inputs finite
}
__device__ __forceinline__ uint32_t pack2bf(float lo, float hi) {
  return f2bf(lo) | (f2bf(hi) << 16);
}

// --------------------------- kernel 1: normalize ---------------------------
// grid 1024 x 256. Each wave handles one i (both z_i and z_j rows).
__global__ __launch_bounds__(256) void ntx_norm(
    const float* __restrict__ zi, const float* __restrict__ zj,
    uint32_t* __restrict__ zn,   // packed 2xbf16, [TOTAL][64]
    float* __restrict__ pos,     // [NHALF]
    unsigned* __restrict__ ticket)
{
  const int t = threadIdx.x;
  if (blockIdx.x == 0 && t == 0) ticket[0] = 0u;   // re-arm last-block gate

  const int wave = t >> 6, lane = t & 63;
  const int i = blockIdx.x * 4 + wave;

  const float2 vi = *(const float2*)(zi + (size_t)i * DK + lane * 2);
  const float2 vj = *(const float2*)(zj + (size_t)i * DK + lane * 2);
  float ssi = vi.x * vi.x + vi.y * vi.y;
  float ssj = vj.x * vj.x + vj.y * vj.y;
  float dij = vi.x * vj.x + vi.y * vj.y;
#pragma unroll
  for (int m = 1; m <= 32; m <<= 1) {
    ssi += __shfl_xor(ssi, m, 64);
    ssj += __shfl_xor(ssj, m, 64);
    dij += __shfl_xor(dij, m, 64);
  }
  const float invi = 1.0f / fmaxf(sqrtf(ssi), 1e-12f);
  const float invj = 1.0f / fmaxf(sqrtf(ssj), 1e-12f);

  zn[(size_t)i * 64 + lane] =
      pack2bf(vi.x * invi * SCALE, vi.y * invi * SCALE);
  zn[(size_t)(i + NHALF) * 64 + lane] =
      pack2bf(vj.x * invj * SCALE, vj.y * invj * SCALE);
  if (lane == 0) pos[i] = dij * invi * invj * TEMP_INV;
}

// ---------------- kernel 2: symmetric Gram + exp partial sums --------------
// grid NBLK x 512. Linear block id -> upper-triangular tile (I, J), J >= I.
// Wave w owns rows [i0+16w, i0+16w+16) x all 128 cols.   (EXACT v7 body.)
// Fragment layout (verified): frag[k=q*8+kk*32+j][m-or-n=c]
//   A -> z[rowbase+c][kk*32+q*8 ..+8] ; B -> lds row (jt*16+c), 16B (kk*4+q)
__global__ __launch_bounds__(512, 8) void ntx_gemm(
    const uint16_t* __restrict__ z,   // [TOTAL][DK] bf16 (scaled)
    float* __restrict__ scratch)      // [NBLK][256]: 128 row + 128 col parts
{
  __shared__ uint4 lb4[TILE * 17];    // 128 rows x (256B data + 16B pad)
  __shared__ float colacc[WAVES][TILE];

  // closed-form triangle decode: largest I with TRI(I) <= bid
  const int bid = (int)blockIdx.x;
  int I = (int)((129.0f - sqrtf(16641.0f - 8.0f * (float)bid)) * 0.5f);
  I = (I < 0) ? 0 : ((I > 63) ? 63 : I);
  while (TRI(I + 1) <= bid) ++I;       // <=1 step fixup for float rounding
  while (TRI(I) > bid) --I;
  const int J = I + (bid - TRI(I));
  const bool isdiag = (I == J);

  const int t = threadIdx.x;
  const int w = t >> 6, lane = t & 63;
  const int q = lane >> 4, c = lane & 15;
  const int i0 = I * TILE;
  const int j0 = J * TILE;
  const int rowbase = i0 + w * 16;

  // A fragment: this wave's 16 rows, 4 k-steps (issue before staging so the
  // scattered-load latency hides under the stage + barrier).
  bf16x8 afrag[4];
  {
    const uint16_t* ap = z + (size_t)(rowbase + c) * DK + q * 8;
#pragma unroll
    for (int kk = 0; kk < 4; ++kk)
      afrag[kk] = *(const bf16x8*)(ap + kk * 32);
  }

  // stage the full B panel (rows j0..j0+127 of z), coalesced 16B/thread.
  {
    const int r0 = t >> 4, ch = t & 15;
#pragma unroll
    for (int p = 0; p < 4; ++p) {
      const int r = r0 + p * 32;
      lb4[r * 17 + ch] = *(const uint4*)(z + (size_t)(j0 + r) * DK + ch * 8);
    }
  }
  __syncthreads();

  float runsum[4] = {0.0f, 0.0f, 0.0f, 0.0f};

#pragma unroll
  for (int jt = 0; jt < TILE / 16; ++jt) {
    const int jc = j0 + jt * 16;       // col = jc + c
    bf16x8 bfrag[4];
#pragma unroll
    for (int kk = 0; kk < 4; ++kk)
      bfrag[kk] = *(const bf16x8*)&lb4[(jt * 16 + c) * 17 + kk * 4 + q];

    floatx4 acc = {0.0f, 0.0f, 0.0f, 0.0f};
#pragma unroll
    for (int kk = 0; kk < 4; ++kk)
      acc = __builtin_amdgcn_mfma_f32_16x16x32_bf16(afrag[kk], bfrag[kk],
                                                    acc, 0, 0, 0);
    // row = rowbase + q*4 + r
    if (isdiag && jc == rowbase) {       // diagonal 16x16 (wave-uniform)
#pragma unroll
      for (int r = 0; r < 4; ++r) {
        float e = EXP2(acc[r]);
        runsum[r] += (q * 4 + r == c) ? 0.0f : e;
      }
    } else {
      float colv = 0.0f;
#pragma unroll
      for (int r = 0; r < 4; ++r) {
        float e = EXP2(acc[r]);
        runsum[r] += e;
        colv += e;
      }
      if (!isdiag) {
        // col sums over this wave's 16 rows: combine the 4 q-groups
        colv += __shfl_xor(colv, 16, 64);
        colv += __shfl_xor(colv, 32, 64);
        if (lane < 16) colacc[w][jt * 16 + lane] = colv;
      }
    }
  }

  // row partials: reduce across the 16 c-lanes (same q), store per block
  float* sblk = scratch + (size_t)bid * 256;
#pragma unroll
  for (int r = 0; r < 4; ++r) {
    float v = runsum[r];
    v += __shfl_xor(v, 1, 64);
    v += __shfl_xor(v, 2, 64);
    v += __shfl_xor(v, 4, 64);
    v += __shfl_xor(v, 8, 64);
    if (c == 0) sblk[w * 16 + q * 4 + r] = v;
  }

  // column partials: combine the 8 waves (off-diagonal blocks only)
  __syncthreads();
  if (!isdiag && t < TILE) {
    float s = 0.0f;
#pragma unroll
    for (int ww = 0; ww < WAVES; ++ww) s += colacc[ww][t];
    sblk[128 + t] = s;
  }
}

// ------------- kernel 3: gather partials, log-reduce, finalize -------------
// grid 64 x 512. Block I handles rows [128I, 128I+128).
// rowsum_i = sum_{J=I..63} scratch[id(I,J)][o] + sum_{I'<I} scratch[id(I',I)][128+o]
// id(I,J) = TRI(I) + (J-I);  id(I',I) = TRI(I') + (I-I').
// 4 gather groups (g = t>>7): g0/g1 row-partials (even/odd J offsets),
// g2/g3 col-partials (even/odd I').  Halves each serial gather chain.
// Last block to finish (device-scope ticket) reduces lpart + pos -> out.
__global__ __launch_bounds__(512) void ntx_redufin(
    const float* __restrict__ scratch, const float* __restrict__ pos,
    float* __restrict__ lpart, unsigned* __restrict__ ticket,
    float* __restrict__ out)
{
  __shared__ float sh[3][128];
  __shared__ float red[8];
  __shared__ int amLast;

  const int I = (int)blockIdx.x;
  const int t = (int)threadIdx.x;
  const int o = t & 127;
  const int g = t >> 7;

  float S = 0.0f;
  if (g < 2) {
    // row partials: id = TRI(I) + d, d = 0..(63-I), split even/odd d
    const int base = TRI(I);
    const int dmax = TILES - 1 - I;
#pragma unroll 4
    for (int d = g; d <= dmax; d += 2)
      S += scratch[(size_t)(base + d) * 256 + o];
  } else {
    // col partials: tiles (Ip, I), Ip < I, split even/odd Ip
#pragma unroll 4
    for (int Ip = g - 2; Ip < I; Ip += 2) {
      const int idc = TRI(Ip) + (I - Ip);
      S += scratch[(size_t)idc * 256 + 128 + o];
    }
  }
  if (g > 0) sh[g - 1][o] = S;
  __syncthreads();
  if (g == 0) {
    float v = __logf(S + sh[0][o] + sh[1][o] + sh[2][o]);
#pragma unroll
    for (int m = 1; m <= 32; m <<= 1) v += __shfl_xor(v, m, 64);
    if ((o & 63) == 0) red[o >> 6] = v;
  }
  __syncthreads();
  if (t == 0) {
    atomicExch(&lpart[I], red[0] + red[1]);   // device-scope store
    __threadfence();                          // release before ticket
    const unsigned done = atomicAdd(ticket, 1u);
    amLast = (done == (unsigned)(TILES - 1));
  }
  __syncthreads();
  if (!amLast) return;

  // ---- last block: deterministic final reduction ----
  __threadfence();                            // acquire side
  float acc = 0.0f;
  if (t < TILES) acc = atomicAdd(&lpart[t], 0.0f);   // coherent read
  for (int r = t; r < NHALF; r += 512) acc -= 2.0f * pos[r];
#pragma unroll
  for (int m = 1; m <= 32; m <<= 1) acc += __shfl_xor(acc, m, 64);
  __syncthreads();                            // red[] reuse
  if ((t & 63) == 0) red[t >> 6] = acc;
  __syncthreads();
  if (t == 0) {
    float s = 0.0f;
#pragma unroll
    for (int wv = 0; wv < 8; ++wv) s += red[wv];
    out[0] = s / (float)TOTAL;
  }
}

// ---------------------------------------------------------------------------
extern "C" void kernel_launch(void* const* d_in, const int* in_sizes, int n_in,
                              void* d_out, int out_size, void* d_ws,
                              size_t ws_size, hipStream_t stream) {
  const float* zi = (const float*)d_in[0];
  const float* zj = (const float*)d_in[1];
  float* out = (float*)d_out;

  char* ws = (char*)d_ws;
  uint16_t* zn      = (uint16_t*)ws;                          // 2 MiB bf16
  size_t off = (size_t)TOTAL * DK * 2;
  float*    scratch = (float*)(ws + off);                     // 2.13 MB
  off += (size_t)NBLK * 256 * 4;
  float*    lpart   = (float*)(ws + off);                     // 256 B
  off += 256 * 4;
  float*    pos     = (float*)(ws + off);                     // 16 KB
  off += (size_t)NHALF * 4;
  unsigned* ticket  = (unsigned*)(ws + off);                  // 4 B

  ntx_norm<<<dim3(NHALF / 4), dim3(256), 0, stream>>>(zi, zj, (uint32_t*)zn,
                                                      pos, ticket);
  ntx_gemm<<<dim3(NBLK), dim3(512), 0, stream>>>(zn, scratch);
  ntx_redufin<<<dim3(TILES), dim3(512), 0, stream>>>(scratch, pos, lpart,
                                                     ticket, out);
}

// Round 10
// 89.525 us; speedup vs baseline: 1.1937x; 1.0091x over previous
//
#include <hip/hip_runtime.h>
#include <stdint.h>

// ---------------------------------------------------------------------------
// NT-Xent loss, B=8 S=512 D=128  ->  N=4096, 2N=8192 rows, K=128.
// loss = mean_i( -pos_i + log(sum_{j!=i} exp(sim_ij)) ),  sim = z_n z_n^T / T
//
// v11: v10 with a half-panel software pipeline in the gemm (T14 async-STAGE
// split).  v7's proven body had a fully serial prologue: 32KB panel stage +
// barrier before any compute.  Now: stage rows 0..63; barrier; ISSUE the
// rows 64..127 loads into registers; compute jt 0..3 (touches LDS rows
// 0..63 only) while those loads fly; ds_write them to the disjoint LDS
// region; barrier; compute jt 4..7.  Halves the exposed stage latency and
// hides the other half under compute.  Everything else (fragment layout,
// padded LDS, diag exclusion, scratch, redufin, norm, ticket) unchanged.
//
//  k1: normalize rows (fp32), pos_half in fp32, store z_n * SCALE as bf16
//      where SCALE^2 = log2(e)/T, so MFMA acc = sim*log2e and
//      exp(sim) == exp2(acc) == one v_exp_f32.  Also re-arms the ticket.
//  k2: symmetric Gram + exp row/col partial sums -> scratch[blk][256]
//      (2080 upper-triangle 128x128 tiles; no atomics).
//  k3: ntx_redufin: block I gathers the 64 partials per row (triangular
//      indexing, 4-way split), lpart[I] = sum log(rowsum); last block
//      (ticket) deterministically reduces lpart[0..63] - 2*sum(pos) -> out.
// No max-subtraction needed: logits in [-14.3,14.3], sums < 1.3e10 (fp32-safe).
// ---------------------------------------------------------------------------

#define TOTAL   8192
#define NHALF   4096
#define DK      128
#define TEMP_INV 14.285714285714286f
#define SCALE    4.539816f      // sqrt(log2(e)/0.07); SCALE^2 = 20.609929

#define TILE    128                       // square tile edge
#define TILES   (TOTAL / TILE)            // 64
#define NBLK    (TILES * (TILES + 1) / 2) // 2080 super-diagonal tiles
#define WAVES   8

// TRI(I) = number of tiles before row I = I*(2*TILES+1-I)/2, TILES=64
#define TRI(I) (((I) * (129 - (I))) >> 1)

typedef short  bf16x8  __attribute__((ext_vector_type(8)));
typedef float  floatx4 __attribute__((ext_vector_type(4)));

#if __has_builtin(__builtin_amdgcn_exp2f)
#define EXP2(x) __builtin_amdgcn_exp2f(x)
#else
#define EXP2(x) exp2f(x)
#endif

__device__ __forceinline__ uint32_t f2bf(float f) {
  uint32_t u = __float_as_uint(f);
  return (u + 0x7fffu + ((u >> 16) & 1u)) >> 16;   // RNE; inputs finite
}
__device__ __forceinline__ uint32_t pack2bf(float lo, float hi) {
  return f2bf(lo) | (f2bf(hi) << 16);
}

// --------------------------- kernel 1: normalize ---------------------------
// grid 1024 x 256. Each wave handles one i (both z_i and z_j rows).
__global__ __launch_bounds__(256) void ntx_norm(
    const float* __restrict__ zi, const float* __restrict__ zj,
    uint32_t* __restrict__ zn,   // packed 2xbf16, [TOTAL][64]
    float* __restrict__ pos,     // [NHALF]
    unsigned* __restrict__ ticket)
{
  const int t = threadIdx.x;
  if (blockIdx.x == 0 && t == 0) ticket[0] = 0u;   // re-arm last-block gate

  const int wave = t >> 6, lane = t & 63;
  const int i = blockIdx.x * 4 + wave;

  const float2 vi = *(const float2*)(zi + (size_t)i * DK + lane * 2);
  const float2 vj = *(const float2*)(zj + (size_t)i * DK + lane * 2);
  float ssi = vi.x * vi.x + vi.y * vi.y;
  float ssj = vj.x * vj.x + vj.y * vj.y;
  float dij = vi.x * vj.x + vi.y * vj.y;
#pragma unroll
  for (int m = 1; m <= 32; m <<= 1) {
    ssi += __shfl_xor(ssi, m, 64);
    ssj += __shfl_xor(ssj, m, 64);
    dij += __shfl_xor(dij, m, 64);
  }
  const float invi = 1.0f / fmaxf(sqrtf(ssi), 1e-12f);
  const float invj = 1.0f / fmaxf(sqrtf(ssj), 1e-12f);

  zn[(size_t)i * 64 + lane] =
      pack2bf(vi.x * invi * SCALE, vi.y * invi * SCALE);
  zn[(size_t)(i + NHALF) * 64 + lane] =
      pack2bf(vj.x * invj * SCALE, vj.y * invj * SCALE);
  if (lane == 0) pos[i] = dij * invi * invj * TEMP_INV;
}

// ---------------- kernel 2: symmetric Gram + exp partial sums --------------
// grid NBLK x 512. Linear block id -> upper-triangular tile (I, J), J >= I.
// Wave w owns rows [i0+16w, i0+16w+16) x all 128 cols.  (v7 body + pipeline.)
// Fragment layout (verified): frag[k=q*8+kk*32+j][m-or-n=c]
//   A -> z[rowbase+c][kk*32+q*8 ..+8] ; B -> lds row (jt*16+c), 16B (kk*4+q)
__global__ __launch_bounds__(512, 8) void ntx_gemm(
    const uint16_t* __restrict__ z,   // [TOTAL][DK] bf16 (scaled)
    float* __restrict__ scratch)      // [NBLK][256]: 128 row + 128 col parts
{
  __shared__ uint4 lb4[TILE * 17];    // 128 rows x (256B data + 16B pad)
  __shared__ float colacc[WAVES][TILE];

  // closed-form triangle decode: largest I with TRI(I) <= bid
  const int bid = (int)blockIdx.x;
  int I = (int)((129.0f - sqrtf(16641.0f - 8.0f * (float)bid)) * 0.5f);
  I = (I < 0) ? 0 : ((I > 63) ? 63 : I);
  while (TRI(I + 1) <= bid) ++I;       // <=1 step fixup for float rounding
  while (TRI(I) > bid) --I;
  const int J = I + (bid - TRI(I));
  const bool isdiag = (I == J);

  const int t = threadIdx.x;
  const int w = t >> 6, lane = t & 63;
  const int q = lane >> 4, c = lane & 15;
  const int i0 = I * TILE;
  const int j0 = J * TILE;
  const int rowbase = i0 + w * 16;

  // A fragment: this wave's 16 rows, 4 k-steps (issue first; latency hides
  // under the half-0 stage + barrier).
  bf16x8 afrag[4];
  {
    const uint16_t* ap = z + (size_t)(rowbase + c) * DK + q * 8;
#pragma unroll
    for (int kk = 0; kk < 4; ++kk)
      afrag[kk] = *(const bf16x8*)(ap + kk * 32);
  }

  const int r0 = t >> 4, ch = t & 15;   // staging coords (r0: 0..31)

  // ---- stage half 0 (panel rows 0..63), 2x16B per thread, coalesced ----
  lb4[r0 * 17 + ch] =
      *(const uint4*)(z + (size_t)(j0 + r0) * DK + ch * 8);
  lb4[(r0 + 32) * 17 + ch] =
      *(const uint4*)(z + (size_t)(j0 + r0 + 32) * DK + ch * 8);
  __syncthreads();

  // ---- issue half-1 prefetch into registers (flies under phase A) ----
  const uint4 pre0 = *(const uint4*)(z + (size_t)(j0 + 64 + r0) * DK + ch * 8);
  const uint4 pre1 = *(const uint4*)(z + (size_t)(j0 + 96 + r0) * DK + ch * 8);

  float runsum[4] = {0.0f, 0.0f, 0.0f, 0.0f};

  // one jt step (16 cols) of the inner loop -- identical math to v7/v10
#define COMP_JT(jt)                                                          \
  {                                                                          \
    const int jc = j0 + (jt) * 16;                                           \
    bf16x8 bfrag[4];                                                         \
    _Pragma("unroll")                                                        \
    for (int kk = 0; kk < 4; ++kk)                                           \
      bfrag[kk] = *(const bf16x8*)&lb4[((jt) * 16 + c) * 17 + kk * 4 + q];   \
    floatx4 acc = {0.0f, 0.0f, 0.0f, 0.0f};                                  \
    _Pragma("unroll")                                                        \
    for (int kk = 0; kk < 4; ++kk)                                           \
      acc = __builtin_amdgcn_mfma_f32_16x16x32_bf16(afrag[kk], bfrag[kk],    \
                                                    acc, 0, 0, 0);           \
    if (isdiag && jc == rowbase) {      /* diagonal 16x16 (wave-uniform) */  \
      _Pragma("unroll")                                                      \
      for (int r = 0; r < 4; ++r) {                                          \
        float e = EXP2(acc[r]);                                              \
        runsum[r] += (q * 4 + r == c) ? 0.0f : e;                            \
      }                                                                      \
    } else {                                                                 \
      float colv = 0.0f;                                                     \
      _Pragma("unroll")                                                      \
      for (int r = 0; r < 4; ++r) {                                          \
        float e = EXP2(acc[r]);                                              \
        runsum[r] += e;                                                      \
        colv += e;                                                           \
      }                                                                      \
      if (!isdiag) {                                                         \
        colv += __shfl_xor(colv, 16, 64);                                    \
        colv += __shfl_xor(colv, 32, 64);                                    \
        if (lane < 16) colacc[w][(jt) * 16 + lane] = colv;                   \
      }                                                                      \
    }                                                                        \
  }

  // ---- phase A: jt 0..3 (LDS rows 0..63 only) ----
  COMP_JT(0) COMP_JT(1) COMP_JT(2) COMP_JT(3)

  // ---- land half 1 (LDS rows 64..127: disjoint from phase-A reads, so no
  // barrier needed before the writes; barrier after makes them visible) ----
  lb4[(r0 + 64) * 17 + ch] = pre0;
  lb4[(r0 + 96) * 17 + ch] = pre1;
  __syncthreads();

  // ---- phase B: jt 4..7 ----
  COMP_JT(4) COMP_JT(5) COMP_JT(6) COMP_JT(7)
#undef COMP_JT

  // row partials: reduce across the 16 c-lanes (same q), store per block
  float* sblk = scratch + (size_t)bid * 256;
#pragma unroll
  for (int r = 0; r < 4; ++r) {
    float v = runsum[r];
    v += __shfl_xor(v, 1, 64);
    v += __shfl_xor(v, 2, 64);
    v += __shfl_xor(v, 4, 64);
    v += __shfl_xor(v, 8, 64);
    if (c == 0) sblk[w * 16 + q * 4 + r] = v;
  }

  // column partials: combine the 8 waves (off-diagonal blocks only)
  __syncthreads();
  if (!isdiag && t < TILE) {
    float s = 0.0f;
#pragma unroll
    for (int ww = 0; ww < WAVES; ++ww) s += colacc[ww][t];
    sblk[128 + t] = s;
  }
}

// ------------- kernel 3: gather partials, log-reduce, finalize -------------
// grid 64 x 512. Block I handles rows [128I, 128I+128).
// rowsum_i = sum_{J=I..63} scratch[id(I,J)][o] + sum_{I'<I} scratch[id(I',I)][128+o]
// id(I,J) = TRI(I) + (J-I);  id(I',I) = TRI(I') + (I-I').
// 4 gather groups (g = t>>7): g0/g1 row-partials (even/odd J offsets),
// g2/g3 col-partials (even/odd I').  Halves each serial gather chain.
// Last block to finish (device-scope ticket) reduces lpart + pos -> out.
__global__ __launch_bounds__(512) void ntx_redufin(
    const float* __restrict__ scratch, const float* __restrict__ pos,
    float* __restrict__ lpart, unsigned* __restrict__ ticket,
    float* __restrict__ out)
{
  __shared__ float sh[3][128];
  __shared__ float red[8];
  __shared__ int amLast;

  const int I = (int)blockIdx.x;
  const int t = (int)threadIdx.x;
  const int o = t & 127;
  const int g = t >> 7;

  float S = 0.0f;
  if (g < 2) {
    // row partials: id = TRI(I) + d, d = 0..(63-I), split even/odd d
    const int base = TRI(I);
    const int dmax = TILES - 1 - I;
#pragma unroll 4
    for (int d = g; d <= dmax; d += 2)
      S += scratch[(size_t)(base + d) * 256 + o];
  } else {
    // col partials: tiles (Ip, I), Ip < I, split even/odd Ip
#pragma unroll 4
    for (int Ip = g - 2; Ip < I; Ip += 2) {
      const int idc = TRI(Ip) + (I - Ip);
      S += scratch[(size_t)idc * 256 + 128 + o];
    }
  }
  if (g > 0) sh[g - 1][o] = S;
  __syncthreads();
  if (g == 0) {
    float v = __logf(S + sh[0][o] + sh[1][o] + sh[2][o]);
#pragma unroll
    for (int m = 1; m <= 32; m <<= 1) v += __shfl_xor(v, m, 64);
    if ((o & 63) == 0) red[o >> 6] = v;
  }
  __syncthreads();
  if (t == 0) {
    atomicExch(&lpart[I], red[0] + red[1]);   // device-scope store
    __threadfence();                          // release before ticket
    const unsigned done = atomicAdd(ticket, 1u);
    amLast = (done == (unsigned)(TILES - 1));
  }
  __syncthreads();
  if (!amLast) return;

  // ---- last block: deterministic final reduction ----
  __threadfence();                            // acquire side
  float acc = 0.0f;
  if (t < TILES) acc = atomicAdd(&lpart[t], 0.0f);   // coherent read
  for (int r = t; r < NHALF; r += 512) acc -= 2.0f * pos[r];
#pragma unroll
  for (int m = 1; m <= 32; m <<= 1) acc += __shfl_xor(acc, m, 64);
  __syncthreads();                            // red[] reuse
  if ((t & 63) == 0) red[t >> 6] = acc;
  __syncthreads();
  if (t == 0) {
    float s = 0.0f;
#pragma unroll
    for (int wv = 0; wv < 8; ++wv) s += red[wv];
    out[0] = s / (float)TOTAL;
  }
}

// ---------------------------------------------------------------------------
extern "C" void kernel_launch(void* const* d_in, const int* in_sizes, int n_in,
                              void* d_out, int out_size, void* d_ws,
                              size_t ws_size, hipStream_t stream) {
  const float* zi = (const float*)d_in[0];
  const float* zj = (const float*)d_in[1];
  float* out = (float*)d_out;

  char* ws = (char*)d_ws;
  uint16_t* zn      = (uint16_t*)ws;                          // 2 MiB bf16
  size_t off = (size_t)TOTAL * DK * 2;
  float*    scratch = (float*)(ws + off);                     // 2.13 MB
  off += (size_t)NBLK * 256 * 4;
  float*    lpart   = (float*)(ws + off);                     // 256 B
  off += 256 * 4;
  float*    pos     = (float*)(ws + off);                     // 16 KB
  off += (size_t)NHALF * 4;
  unsigned* ticket  = (unsigned*)(ws + off);                  // 4 B

  ntx_norm<<<dim3(NHALF / 4), dim3(256), 0, stream>>>(zi, zj, (uint32_t*)zn,
                                                      pos, ticket);
  ntx_gemm<<<dim3(NBLK), dim3(512), 0, stream>>>(zn, scratch);
  ntx_redufin<<<dim3(TILES), dim3(512), 0, stream>>>(scratch, pos, lpart,
                                                     ticket, out);
}